// Round 12
// baseline (146.545 us; speedup 1.0000x reference)
//
#include <hip/hip_runtime.h>

typedef unsigned short u16;
typedef unsigned int u32;
typedef __attribute__((ext_vector_type(8))) short short8;
typedef __attribute__((ext_vector_type(4))) float f32x4;
typedef __attribute__((ext_vector_type(4))) u16 u16x4;

#define NBATCH 2
#define NC 128
#define NN 147456          // 16*96*96
#define CH 64              // gram k-depth per chunk (double-buffered)
#define NCH (NN / CH)      // 2304 chunks per batch
#define G1_PARTS 256       // gram blocks per batch -> 9 chunks per block
#define N3_PER_B 1152      // NN / 128 n-tiles per batch (stage 3)

__device__ __forceinline__ u16 bf16rne(float f) {
  u32 u = __builtin_bit_cast(u32, f);
  return (u16)((u + 0x7FFFu + ((u >> 16) & 1u)) >> 16);
}
__device__ __forceinline__ float bf2f(u16 h) {
  u32 u = ((u32)h) << 16;
  return __builtin_bit_cast(float, u);
}
// truncation split: h = top16(f), g = rne(f - h)
__device__ __forceinline__ void split2(float f, u16& h, u16& g) {
  u32 u = __builtin_bit_cast(u32, f);
  h = (u16)(u >> 16);
  float hf = __builtin_bit_cast(float, u & 0xFFFF0000u);
  g = bf16rne(f - hf);
}

// ---------------------------------------------------------------------------
// Stage 1: partial Gram, BK=64 double-buffered software pipeline (unchanged,
// measured ~26 us ~= HBM floor).
// ---------------------------------------------------------------------------
__global__ __launch_bounds__(256, 2)
void gram_k(const float* __restrict__ x, float* __restrict__ part) {
  __shared__ u16 hi[2][128 * CH];
  __shared__ u16 lo[2][128 * CH];
  const int tid = threadIdx.x;
  const int bid = blockIdx.x;
  const int b   = bid >> 8;
  const int pi  = bid & 255;
  const int w   = tid >> 6;
  const int l   = tid & 63;
  const int grp = l >> 4;
  const int lr  = l & 15;
  const int swz = (lr & 7) << 3;
  const float* xb = x + (size_t)b * NC * NN;

  const int col4 = tid & 15;
  const int r0   = tid >> 4;

  f32x4 acc[2][8];
#pragma unroll
  for (int i = 0; i < 2; ++i)
#pragma unroll
    for (int j = 0; j < 8; ++j) acc[i][j] = (f32x4){0.f, 0.f, 0.f, 0.f};

  float4 v[8];

  auto issue = [&](int ch) {
    const int k0 = ch * CH + (col4 << 2);
#pragma unroll
    for (int j = 0; j < 8; ++j)
      v[j] = *(const float4*)(xb + (size_t)(r0 + (j << 4)) * NN + k0);
  };
  auto stage = [&](int bb) {
    u16* H = &hi[bb][0];
    u16* L = &lo[bb][0];
#pragma unroll
    for (int j = 0; j < 8; ++j) {
      const int row = r0 + (j << 4);
      const int idx = (row << 6) + ((col4 << 2) ^ ((row & 7) << 3));
      u16 h0, h1, h2, h3, g0, g1, g2, g3;
      split2(v[j].x, h0, g0); split2(v[j].y, h1, g1);
      split2(v[j].z, h2, g2); split2(v[j].w, h3, g3);
      *(u16x4*)(H + idx) = (u16x4){h0, h1, h2, h3};
      *(u16x4*)(L + idx) = (u16x4){g0, g1, g2, g3};
    }
  };
  const int m0 = (w << 5) + lr;
  const int m1 = m0 + 16;
  auto mma = [&](int bb) {
    const u16* H = &hi[bb][0];
    const u16* L = &lo[bb][0];
#pragma unroll
    for (int kk = 0; kk < CH; kk += 32) {
      const int kv = (kk + (grp << 3)) ^ swz;
      const short8 Ah0 = *(const short8*)(H + (m0 << 6) + kv);
      const short8 Al0 = *(const short8*)(L + (m0 << 6) + kv);
      const short8 Ah1 = *(const short8*)(H + (m1 << 6) + kv);
      const short8 Al1 = *(const short8*)(L + (m1 << 6) + kv);
#pragma unroll
      for (int nt = 0; nt < 8; ++nt) {
        const int nr  = (nt << 4) + lr;
        const int bix = (nr << 6) + kv;
        const short8 Bh = *(const short8*)(H + bix);
        const short8 Bl = *(const short8*)(L + bix);
        acc[0][nt] = __builtin_amdgcn_mfma_f32_16x16x32_bf16(Ah0, Bh, acc[0][nt], 0, 0, 0);
        acc[0][nt] = __builtin_amdgcn_mfma_f32_16x16x32_bf16(Ah0, Bl, acc[0][nt], 0, 0, 0);
        acc[0][nt] = __builtin_amdgcn_mfma_f32_16x16x32_bf16(Al0, Bh, acc[0][nt], 0, 0, 0);
        acc[1][nt] = __builtin_amdgcn_mfma_f32_16x16x32_bf16(Ah1, Bh, acc[1][nt], 0, 0, 0);
        acc[1][nt] = __builtin_amdgcn_mfma_f32_16x16x32_bf16(Ah1, Bl, acc[1][nt], 0, 0, 0);
        acc[1][nt] = __builtin_amdgcn_mfma_f32_16x16x32_bf16(Al1, Bh, acc[1][nt], 0, 0, 0);
      }
    }
  };

  issue(pi);
  stage(0);
  __syncthreads();

  const int NITER = NCH / G1_PARTS;  // 9
  for (int i = 0; i < NITER; ++i) {
    if (i + 1 < NITER) issue(pi + (i + 1) * G1_PARTS);
    mma(i & 1);
    if (i + 1 < NITER) stage((i + 1) & 1);
    __syncthreads();
  }

  float* pb = part + (size_t)bid * 16384;
#pragma unroll
  for (int mt = 0; mt < 2; ++mt)
#pragma unroll
    for (int nt = 0; nt < 8; ++nt)
#pragma unroll
      for (int r = 0; r < 4; ++r) {
        const int row = (w << 5) + (mt << 4) + (grp << 2) + r;
        const int col = (nt << 4) + lr;
        pb[(row << 7) + col] = acc[mt][nt][r];
      }
}

// ---------------------------------------------------------------------------
// Stage 2: reduce partials + softmax(-energy), emit bf16 attn to ws.
// ---------------------------------------------------------------------------
__global__ __launch_bounds__(128)
void soft_k(const float* __restrict__ part, u16* __restrict__ attn) {
  const int b = blockIdx.x >> 7;
  const int c = blockIdx.x & 127;
  const int d = threadIdx.x;
  __shared__ float red[128];
  float e = 0.f;
  const float* p0 = part + ((size_t)(b * G1_PARTS) << 14) + (c << 7) + d;
  for (int p = 0; p < G1_PARTS; ++p) e += p0[(size_t)p << 14];
  red[d] = e;
  __syncthreads();
#pragma unroll
  for (int s = 64; s > 0; s >>= 1) {
    if (d < s) red[d] = fminf(red[d], red[d + s]);
    __syncthreads();
  }
  const float emin = red[0];
  __syncthreads();
  const float pr = __expf(emin - e);
  red[d] = pr;
  __syncthreads();
#pragma unroll
  for (int s = 64; s > 0; s >>= 1) {
    if (d < s) red[d] += red[d + s];
    __syncthreads();
  }
  const float inv = 1.f / red[0];
  attn[(((size_t)b) << 14) + (c << 7) + d] = bf16rne(pr * inv);
}

// ---------------------------------------------------------------------------
// Stage 3 v10: measured-best v8 structure + hi-u16 B-loads.
// PV needs only the hi-16 of x (lo-term dropped, convex attn rows), so load
// ((const u16*)x)[2*idx+1] directly: no bf16rne chains in the k-loop (64
// 3-op cvt chains deleted per thread; pack = v_perm).  Same cache lines as
// before (epilogue f32 reads reuse them).  Lower VGPR -> launch_bounds(256,5).
// attn in LDS (XOR swizzle); adjacent load-x/store-out epilogue (1x WRITE).
// ---------------------------------------------------------------------------
__global__ __launch_bounds__(256, 5)
void pv_k(const float* __restrict__ x, const u16* __restrict__ attn,
          const float* __restrict__ gamma, float* __restrict__ out) {
  __shared__ u16 at[128 * 128];   // 32 KiB
  const int tid = threadIdx.x;
  const int bid = blockIdx.x;
  const int b   = bid / N3_PER_B;
  const int nb  = (bid % N3_PER_B) << 7;
  const int w = tid >> 6, l = tid & 63, grp = l >> 4, lr = l & 15;
  const int swz = lr << 3;
  const size_t bbase = (size_t)b * NC * NN;
  const u16* xh = (const u16*)(x + bbase);   // u16 view; hi of elem i at [2i+1]
  const u16* ab = attn + ((size_t)b << 14);

#pragma unroll
  for (int j = 0; j < 8; ++j) {
    const int idx = (j << 8) + tid;
    const int c  = idx >> 4;
    const int d0 = (idx & 15) << 3;
    const int dst = (c << 7) + (d0 ^ ((c & 15) << 3));
    *(short8*)(at + dst) = *(const short8*)(ab + (c << 7) + d0);
  }
  __syncthreads();

  f32x4 acc[8][2];
#pragma unroll
  for (int i = 0; i < 8; ++i) {
    acc[i][0] = (f32x4){0.f, 0.f, 0.f, 0.f};
    acc[i][1] = (f32x4){0.f, 0.f, 0.f, 0.f};
  }

  const int n0 = nb + (w << 5) + lr;
#pragma unroll
  for (int kk = 0; kk < 128; kk += 32) {
    const int d0 = kk + (grp << 3);
    short8 Bh[2];
#pragma unroll
    for (int t = 0; t < 2; ++t) {
      const size_t e0 = (size_t)d0 * NN + (n0 + (t << 4));   // element index
      u16 h[8];
#pragma unroll
      for (int i = 0; i < 8; ++i)
        h[i] = xh[((e0 + (size_t)i * NN) << 1) + 1];         // hi-16 of f32
      Bh[t] = (short8){(short)h[0], (short)h[1], (short)h[2], (short)h[3],
                       (short)h[4], (short)h[5], (short)h[6], (short)h[7]};
    }
#pragma unroll
    for (int mt = 0; mt < 8; ++mt) {
      const int mrow = (mt << 4) + lr;
      const short8 Ah = *(const short8*)(at + (mrow << 7) + ((kk + (grp << 3)) ^ swz));
#pragma unroll
      for (int t = 0; t < 2; ++t)
        acc[mt][t] = __builtin_amdgcn_mfma_f32_16x16x32_bf16(Ah, Bh[t], acc[mt][t], 0, 0, 0);
    }
  }

  // epilogue: ADJACENT load-x / store-out per element (the 1x-WRITE pattern)
  const float gm = gamma[0];
#pragma unroll
  for (int mt = 0; mt < 8; ++mt)
#pragma unroll
    for (int t = 0; t < 2; ++t)
#pragma unroll
      for (int r = 0; r < 4; ++r) {
        const int c = (mt << 4) + (grp << 2) + r;
        const int n = n0 + (t << 4);
        const size_t off = bbase + (size_t)c * NN + n;
        out[off] = x[off] + gm * acc[mt][t][r];
      }
}

extern "C" void kernel_launch(void* const* d_in, const int* in_sizes, int n_in,
                              void* d_out, int out_size, void* d_ws, size_t ws_size,
                              hipStream_t stream) {
  (void)in_sizes; (void)n_in; (void)out_size; (void)ws_size;
  const float* x     = (const float*)d_in[0];
  const float* gamma = (const float*)d_in[1];
  float* out  = (float*)d_out;
  u16*   attn = (u16*)d_ws;          // 2*128*128 bf16 = 64 KiB
  float* part = out;                  // reuse d_out as partial-Gram scratch (33.5 MB)

  gram_k<<<dim3(2 * G1_PARTS), dim3(256), 0, stream>>>(x, part);
  soft_k<<<dim3(2 * 128),      dim3(128), 0, stream>>>(part, attn);
  pv_k  <<<dim3(2 * N3_PER_B), dim3(256), 0, stream>>>(x, attn, gamma, out);
}

// Round 13
// 118.841 us; speedup vs baseline: 1.2331x; 1.2331x over previous
//
#include <hip/hip_runtime.h>

typedef unsigned short u16;
typedef unsigned int u32;
typedef __attribute__((ext_vector_type(8))) short short8;
typedef __attribute__((ext_vector_type(4))) float f32x4;
typedef __attribute__((ext_vector_type(4))) u16 u16x4;

#define NBATCH 2
#define NC 128
#define NN 147456          // 16*96*96
#define CH 64              // gram k-depth per chunk (double-buffered)
#define NCH (NN / CH)      // 2304 chunks per batch
#define G1_PARTS 256       // gram blocks per batch -> 9 chunks per block
#define N3_PER_B 1152      // NN / 128 n-tiles per batch (stage 3)

__device__ __forceinline__ u16 bf16rne(float f) {
  u32 u = __builtin_bit_cast(u32, f);
  return (u16)((u + 0x7FFFu + ((u >> 16) & 1u)) >> 16);
}
__device__ __forceinline__ float bf2f(u16 h) {
  u32 u = ((u32)h) << 16;
  return __builtin_bit_cast(float, u);
}
// truncation split: h = top16(f), g = rne(f - h)
__device__ __forceinline__ void split2(float f, u16& h, u16& g) {
  u32 u = __builtin_bit_cast(u32, f);
  h = (u16)(u >> 16);
  float hf = __builtin_bit_cast(float, u & 0xFFFF0000u);
  g = bf16rne(f - hf);
}

// ---------------------------------------------------------------------------
// Stage 1: partial Gram, BK=64 double-buffered software pipeline (unchanged,
// measured ~26 us ~= HBM floor).
// ---------------------------------------------------------------------------
__global__ __launch_bounds__(256, 2)
void gram_k(const float* __restrict__ x, float* __restrict__ part) {
  __shared__ u16 hi[2][128 * CH];
  __shared__ u16 lo[2][128 * CH];
  const int tid = threadIdx.x;
  const int bid = blockIdx.x;
  const int b   = bid >> 8;
  const int pi  = bid & 255;
  const int w   = tid >> 6;
  const int l   = tid & 63;
  const int grp = l >> 4;
  const int lr  = l & 15;
  const int swz = (lr & 7) << 3;
  const float* xb = x + (size_t)b * NC * NN;

  const int col4 = tid & 15;
  const int r0   = tid >> 4;

  f32x4 acc[2][8];
#pragma unroll
  for (int i = 0; i < 2; ++i)
#pragma unroll
    for (int j = 0; j < 8; ++j) acc[i][j] = (f32x4){0.f, 0.f, 0.f, 0.f};

  float4 v[8];

  auto issue = [&](int ch) {
    const int k0 = ch * CH + (col4 << 2);
#pragma unroll
    for (int j = 0; j < 8; ++j)
      v[j] = *(const float4*)(xb + (size_t)(r0 + (j << 4)) * NN + k0);
  };
  auto stage = [&](int bb) {
    u16* H = &hi[bb][0];
    u16* L = &lo[bb][0];
#pragma unroll
    for (int j = 0; j < 8; ++j) {
      const int row = r0 + (j << 4);
      const int idx = (row << 6) + ((col4 << 2) ^ ((row & 7) << 3));
      u16 h0, h1, h2, h3, g0, g1, g2, g3;
      split2(v[j].x, h0, g0); split2(v[j].y, h1, g1);
      split2(v[j].z, h2, g2); split2(v[j].w, h3, g3);
      *(u16x4*)(H + idx) = (u16x4){h0, h1, h2, h3};
      *(u16x4*)(L + idx) = (u16x4){g0, g1, g2, g3};
    }
  };
  const int m0 = (w << 5) + lr;
  const int m1 = m0 + 16;
  auto mma = [&](int bb) {
    const u16* H = &hi[bb][0];
    const u16* L = &lo[bb][0];
#pragma unroll
    for (int kk = 0; kk < CH; kk += 32) {
      const int kv = (kk + (grp << 3)) ^ swz;
      const short8 Ah0 = *(const short8*)(H + (m0 << 6) + kv);
      const short8 Al0 = *(const short8*)(L + (m0 << 6) + kv);
      const short8 Ah1 = *(const short8*)(H + (m1 << 6) + kv);
      const short8 Al1 = *(const short8*)(L + (m1 << 6) + kv);
#pragma unroll
      for (int nt = 0; nt < 8; ++nt) {
        const int nr  = (nt << 4) + lr;
        const int bix = (nr << 6) + kv;
        const short8 Bh = *(const short8*)(H + bix);
        const short8 Bl = *(const short8*)(L + bix);
        acc[0][nt] = __builtin_amdgcn_mfma_f32_16x16x32_bf16(Ah0, Bh, acc[0][nt], 0, 0, 0);
        acc[0][nt] = __builtin_amdgcn_mfma_f32_16x16x32_bf16(Ah0, Bl, acc[0][nt], 0, 0, 0);
        acc[0][nt] = __builtin_amdgcn_mfma_f32_16x16x32_bf16(Al0, Bh, acc[0][nt], 0, 0, 0);
        acc[1][nt] = __builtin_amdgcn_mfma_f32_16x16x32_bf16(Ah1, Bh, acc[1][nt], 0, 0, 0);
        acc[1][nt] = __builtin_amdgcn_mfma_f32_16x16x32_bf16(Ah1, Bl, acc[1][nt], 0, 0, 0);
        acc[1][nt] = __builtin_amdgcn_mfma_f32_16x16x32_bf16(Al1, Bh, acc[1][nt], 0, 0, 0);
      }
    }
  };

  issue(pi);
  stage(0);
  __syncthreads();

  const int NITER = NCH / G1_PARTS;  // 9
  for (int i = 0; i < NITER; ++i) {
    if (i + 1 < NITER) issue(pi + (i + 1) * G1_PARTS);
    mma(i & 1);
    if (i + 1 < NITER) stage((i + 1) & 1);
    __syncthreads();
  }

  float* pb = part + (size_t)bid * 16384;
#pragma unroll
  for (int mt = 0; mt < 2; ++mt)
#pragma unroll
    for (int nt = 0; nt < 8; ++nt)
#pragma unroll
      for (int r = 0; r < 4; ++r) {
        const int row = (w << 5) + (mt << 4) + (grp << 2) + r;
        const int col = (nt << 4) + lr;
        pb[(row << 7) + col] = acc[mt][nt][r];
      }
}

// ---------------------------------------------------------------------------
// Stage 2: reduce partials + softmax(-energy), emit bf16 attn to ws.
// ---------------------------------------------------------------------------
__global__ __launch_bounds__(128)
void soft_k(const float* __restrict__ part, u16* __restrict__ attn) {
  const int b = blockIdx.x >> 7;
  const int c = blockIdx.x & 127;
  const int d = threadIdx.x;
  __shared__ float red[128];
  float e = 0.f;
  const float* p0 = part + ((size_t)(b * G1_PARTS) << 14) + (c << 7) + d;
  for (int p = 0; p < G1_PARTS; ++p) e += p0[(size_t)p << 14];
  red[d] = e;
  __syncthreads();
#pragma unroll
  for (int s = 64; s > 0; s >>= 1) {
    if (d < s) red[d] = fminf(red[d], red[d + s]);
    __syncthreads();
  }
  const float emin = red[0];
  __syncthreads();
  const float pr = __expf(emin - e);
  red[d] = pr;
  __syncthreads();
#pragma unroll
  for (int s = 64; s > 0; s >>= 1) {
    if (d < s) red[d] += red[d + s];
    __syncthreads();
  }
  const float inv = 1.f / red[0];
  attn[(((size_t)b) << 14) + (c << 7) + d] = bf16rne(pr * inv);
}

// ---------------------------------------------------------------------------
// Stage 3 v11: measured-best v8 structure + depth-2 software pipeline on the
// k-loop B-loads: issue kk+1's 16 f32 loads BEFORE packing/MFMAing kk's.
// Doubles in-flight global bytes per wave (the measured MLP shortfall:
// 3.4-3.9 TB/s of ~6.3 achievable at ~10-12KB/CU in flight; need ~22KB).
// All v8 invariants preserved: f32 B-loads direct from global, RNE cvt,
// attn in LDS (XOR swizzle), adjacent load-x/store-out epilogue (1x WRITE).
// Fully-unrolled kk keeps f[kk&1] indices compile-time (no scratch).
// ---------------------------------------------------------------------------
__global__ __launch_bounds__(256, 4)
void pv_k(const float* __restrict__ x, const u16* __restrict__ attn,
          const float* __restrict__ gamma, float* __restrict__ out) {
  __shared__ u16 at[128 * 128];   // 32 KiB
  const int tid = threadIdx.x;
  const int bid = blockIdx.x;
  const int b   = bid / N3_PER_B;
  const int nb  = (bid % N3_PER_B) << 7;
  const int w = tid >> 6, l = tid & 63, grp = l >> 4, lr = l & 15;
  const int swz = lr << 3;
  const size_t bbase = (size_t)b * NC * NN;
  const u16* ab = attn + ((size_t)b << 14);

#pragma unroll
  for (int j = 0; j < 8; ++j) {
    const int idx = (j << 8) + tid;
    const int c  = idx >> 4;
    const int d0 = (idx & 15) << 3;
    const int dst = (c << 7) + (d0 ^ ((c & 15) << 3));
    *(short8*)(at + dst) = *(const short8*)(ab + (c << 7) + d0);
  }
  __syncthreads();

  f32x4 acc[8][2];
#pragma unroll
  for (int i = 0; i < 8; ++i) {
    acc[i][0] = (f32x4){0.f, 0.f, 0.f, 0.f};
    acc[i][1] = (f32x4){0.f, 0.f, 0.f, 0.f};
  }

  const int n0 = nb + (w << 5) + lr;

  float f[2][2][8];   // [buf][t][i] — buf index is compile-time after unroll
  // prologue: loads for kk=0
#pragma unroll
  for (int t = 0; t < 2; ++t) {
    const float* src = x + bbase + (size_t)(grp << 3) * NN + (n0 + (t << 4));
#pragma unroll
    for (int i = 0; i < 8; ++i) f[0][t][i] = src[(size_t)i * NN];
  }

#pragma unroll
  for (int kk = 0; kk < 4; ++kk) {
    const int cur = kk & 1;
    const int nxt = cur ^ 1;
    // issue next kk's 16 loads — in flight across this kk's pack + 16 MFMAs
    if (kk < 3) {
      const int d1 = ((kk + 1) << 5) + (grp << 3);
#pragma unroll
      for (int t = 0; t < 2; ++t) {
        const float* src = x + bbase + (size_t)d1 * NN + (n0 + (t << 4));
#pragma unroll
        for (int i = 0; i < 8; ++i) f[nxt][t][i] = src[(size_t)i * NN];
      }
    }
    // pack current buffer
    short8 Bh[2];
#pragma unroll
    for (int t = 0; t < 2; ++t) {
      u16 h[8];
#pragma unroll
      for (int i = 0; i < 8; ++i) h[i] = bf16rne(f[cur][t][i]);
      Bh[t] = (short8){(short)h[0], (short)h[1], (short)h[2], (short)h[3],
                       (short)h[4], (short)h[5], (short)h[6], (short)h[7]};
    }
#pragma unroll
    for (int mt = 0; mt < 8; ++mt) {
      const int mrow = (mt << 4) + lr;
      const short8 Ah = *(const short8*)(at + (mrow << 7) + (((kk << 5) + (grp << 3)) ^ swz));
#pragma unroll
      for (int t = 0; t < 2; ++t)
        acc[mt][t] = __builtin_amdgcn_mfma_f32_16x16x32_bf16(Ah, Bh[t], acc[mt][t], 0, 0, 0);
    }
  }

  // epilogue: ADJACENT load-x / store-out per element (the 1x-WRITE pattern)
  const float gm = gamma[0];
#pragma unroll
  for (int mt = 0; mt < 8; ++mt)
#pragma unroll
    for (int t = 0; t < 2; ++t)
#pragma unroll
      for (int r = 0; r < 4; ++r) {
        const int c = (mt << 4) + (grp << 2) + r;
        const int n = n0 + (t << 4);
        const size_t off = bbase + (size_t)c * NN + n;
        out[off] = x[off] + gm * acc[mt][t][r];
      }
}

extern "C" void kernel_launch(void* const* d_in, const int* in_sizes, int n_in,
                              void* d_out, int out_size, void* d_ws, size_t ws_size,
                              hipStream_t stream) {
  (void)in_sizes; (void)n_in; (void)out_size; (void)ws_size;
  const float* x     = (const float*)d_in[0];
  const float* gamma = (const float*)d_in[1];
  float* out  = (float*)d_out;
  u16*   attn = (u16*)d_ws;          // 2*128*128 bf16 = 64 KiB
  float* part = out;                  // reuse d_out as partial-Gram scratch (33.5 MB)

  gram_k<<<dim3(2 * G1_PARTS), dim3(256), 0, stream>>>(x, part);
  soft_k<<<dim3(2 * 128),      dim3(128), 0, stream>>>(part, attn);
  pv_k  <<<dim3(2 * N3_PER_B), dim3(256), 0, stream>>>(x, attn, gamma, out);
}

// Round 14
// 115.262 us; speedup vs baseline: 1.2714x; 1.0311x over previous
//
#include <hip/hip_runtime.h>

typedef unsigned short u16;
typedef unsigned int u32;
typedef __attribute__((ext_vector_type(8))) short short8;
typedef __attribute__((ext_vector_type(4))) float f32x4;
typedef __attribute__((ext_vector_type(4))) u16 u16x4;

#define NBATCH 2
#define NC 128
#define NN 147456          // 16*96*96
#define CH 64              // gram k-depth per chunk (double-buffered)
#define NCH (NN / CH)      // 2304 chunks per batch
#define G1_PARTS 256       // gram blocks per batch -> 9 chunks per block
#define N3_PER_B 1152      // NN / 128 n-tiles per batch (stage 3)

__device__ __forceinline__ u16 bf16rne(float f) {
  u32 u = __builtin_bit_cast(u32, f);
  return (u16)((u + 0x7FFFu + ((u >> 16) & 1u)) >> 16);
}
__device__ __forceinline__ float bf2f(u16 h) {
  u32 u = ((u32)h) << 16;
  return __builtin_bit_cast(float, u);
}
// truncation split: h = top16(f), g = rne(f - h)
__device__ __forceinline__ void split2(float f, u16& h, u16& g) {
  u32 u = __builtin_bit_cast(u32, f);
  h = (u16)(u >> 16);
  float hf = __builtin_bit_cast(float, u & 0xFFFF0000u);
  g = bf16rne(f - hf);
}

// ---------------------------------------------------------------------------
// Stage 1: partial Gram, BK=64 double-buffered software pipeline
// (measured ~26 us ~= 92% of achievable HBM read BW).
// ---------------------------------------------------------------------------
__global__ __launch_bounds__(256, 2)
void gram_k(const float* __restrict__ x, float* __restrict__ part) {
  __shared__ u16 hi[2][128 * CH];
  __shared__ u16 lo[2][128 * CH];
  const int tid = threadIdx.x;
  const int bid = blockIdx.x;
  const int b   = bid >> 8;
  const int pi  = bid & 255;
  const int w   = tid >> 6;
  const int l   = tid & 63;
  const int grp = l >> 4;
  const int lr  = l & 15;
  const int swz = (lr & 7) << 3;
  const float* xb = x + (size_t)b * NC * NN;

  const int col4 = tid & 15;
  const int r0   = tid >> 4;

  f32x4 acc[2][8];
#pragma unroll
  for (int i = 0; i < 2; ++i)
#pragma unroll
    for (int j = 0; j < 8; ++j) acc[i][j] = (f32x4){0.f, 0.f, 0.f, 0.f};

  float4 v[8];

  auto issue = [&](int ch) {
    const int k0 = ch * CH + (col4 << 2);
#pragma unroll
    for (int j = 0; j < 8; ++j)
      v[j] = *(const float4*)(xb + (size_t)(r0 + (j << 4)) * NN + k0);
  };
  auto stage = [&](int bb) {
    u16* H = &hi[bb][0];
    u16* L = &lo[bb][0];
#pragma unroll
    for (int j = 0; j < 8; ++j) {
      const int row = r0 + (j << 4);
      const int idx = (row << 6) + ((col4 << 2) ^ ((row & 7) << 3));
      u16 h0, h1, h2, h3, g0, g1, g2, g3;
      split2(v[j].x, h0, g0); split2(v[j].y, h1, g1);
      split2(v[j].z, h2, g2); split2(v[j].w, h3, g3);
      *(u16x4*)(H + idx) = (u16x4){h0, h1, h2, h3};
      *(u16x4*)(L + idx) = (u16x4){g0, g1, g2, g3};
    }
  };
  const int m0 = (w << 5) + lr;
  const int m1 = m0 + 16;
  auto mma = [&](int bb) {
    const u16* H = &hi[bb][0];
    const u16* L = &lo[bb][0];
#pragma unroll
    for (int kk = 0; kk < CH; kk += 32) {
      const int kv = (kk + (grp << 3)) ^ swz;
      const short8 Ah0 = *(const short8*)(H + (m0 << 6) + kv);
      const short8 Al0 = *(const short8*)(L + (m0 << 6) + kv);
      const short8 Ah1 = *(const short8*)(H + (m1 << 6) + kv);
      const short8 Al1 = *(const short8*)(L + (m1 << 6) + kv);
#pragma unroll
      for (int nt = 0; nt < 8; ++nt) {
        const int nr  = (nt << 4) + lr;
        const int bix = (nr << 6) + kv;
        const short8 Bh = *(const short8*)(H + bix);
        const short8 Bl = *(const short8*)(L + bix);
        acc[0][nt] = __builtin_amdgcn_mfma_f32_16x16x32_bf16(Ah0, Bh, acc[0][nt], 0, 0, 0);
        acc[0][nt] = __builtin_amdgcn_mfma_f32_16x16x32_bf16(Ah0, Bl, acc[0][nt], 0, 0, 0);
        acc[0][nt] = __builtin_amdgcn_mfma_f32_16x16x32_bf16(Al0, Bh, acc[0][nt], 0, 0, 0);
        acc[1][nt] = __builtin_amdgcn_mfma_f32_16x16x32_bf16(Ah1, Bh, acc[1][nt], 0, 0, 0);
        acc[1][nt] = __builtin_amdgcn_mfma_f32_16x16x32_bf16(Ah1, Bl, acc[1][nt], 0, 0, 0);
        acc[1][nt] = __builtin_amdgcn_mfma_f32_16x16x32_bf16(Al1, Bh, acc[1][nt], 0, 0, 0);
      }
    }
  };

  issue(pi);
  stage(0);
  __syncthreads();

  const int NITER = NCH / G1_PARTS;  // 9
  for (int i = 0; i < NITER; ++i) {
    if (i + 1 < NITER) issue(pi + (i + 1) * G1_PARTS);
    mma(i & 1);
    if (i + 1 < NITER) stage((i + 1) & 1);
    __syncthreads();
  }

  float* pb = part + (size_t)bid * 16384;
#pragma unroll
  for (int mt = 0; mt < 2; ++mt)
#pragma unroll
    for (int nt = 0; nt < 8; ++nt)
#pragma unroll
      for (int r = 0; r < 4; ++r) {
        const int row = (w << 5) + (mt << 4) + (grp << 2) + r;
        const int col = (nt << 4) + lr;
        pb[(row << 7) + col] = acc[mt][nt][r];
      }
}

// ---------------------------------------------------------------------------
// Stage 2: reduce partials + softmax(-energy), emit bf16 attn to ws.
// ---------------------------------------------------------------------------
__global__ __launch_bounds__(128)
void soft_k(const float* __restrict__ part, u16* __restrict__ attn) {
  const int b = blockIdx.x >> 7;
  const int c = blockIdx.x & 127;
  const int d = threadIdx.x;
  __shared__ float red[128];
  float e = 0.f;
  const float* p0 = part + ((size_t)(b * G1_PARTS) << 14) + (c << 7) + d;
  for (int p = 0; p < G1_PARTS; ++p) e += p0[(size_t)p << 14];
  red[d] = e;
  __syncthreads();
#pragma unroll
  for (int s = 64; s > 0; s >>= 1) {
    if (d < s) red[d] = fminf(red[d], red[d + s]);
    __syncthreads();
  }
  const float emin = red[0];
  __syncthreads();
  const float pr = __expf(emin - e);
  red[d] = pr;
  __syncthreads();
#pragma unroll
  for (int s = 64; s > 0; s >>= 1) {
    if (d < s) red[d] += red[d + s];
    __syncthreads();
  }
  const float inv = 1.f / red[0];
  attn[(((size_t)b) << 14) + (c << 7) + d] = bf16rne(pr * inv);
}

// ---------------------------------------------------------------------------
// Stage 3 v8 (measured best, R10: pv ~86us, total 116.2us):
// attn in LDS (XOR swizzle); B fragments loaded directly from global as f32
// + RNE cvt (hi-only PV: convex attn rows bound |attn@lo| <= ~0.01);
// ADJACENT load-x -> fma -> store-out epilogue (the only pattern measured at
// 1x WRITE); launch_bounds(256,4).
// pv fabric time ~= the runtime's own fillBufferAligned for the same write
// volume -> at the streaming-write fabric floor of this chip.
// ---------------------------------------------------------------------------
__global__ __launch_bounds__(256, 4)
void pv_k(const float* __restrict__ x, const u16* __restrict__ attn,
          const float* __restrict__ gamma, float* __restrict__ out) {
  __shared__ u16 at[128 * 128];   // 32 KiB
  const int tid = threadIdx.x;
  const int bid = blockIdx.x;
  const int b   = bid / N3_PER_B;
  const int nb  = (bid % N3_PER_B) << 7;
  const int w = tid >> 6, l = tid & 63, grp = l >> 4, lr = l & 15;
  const int swz = lr << 3;
  const size_t bbase = (size_t)b * NC * NN;
  const u16* ab = attn + ((size_t)b << 14);

#pragma unroll
  for (int j = 0; j < 8; ++j) {
    const int idx = (j << 8) + tid;
    const int c  = idx >> 4;
    const int d0 = (idx & 15) << 3;
    const int dst = (c << 7) + (d0 ^ ((c & 15) << 3));
    *(short8*)(at + dst) = *(const short8*)(ab + (c << 7) + d0);
  }
  __syncthreads();

  f32x4 acc[8][2];
#pragma unroll
  for (int i = 0; i < 8; ++i) {
    acc[i][0] = (f32x4){0.f, 0.f, 0.f, 0.f};
    acc[i][1] = (f32x4){0.f, 0.f, 0.f, 0.f};
  }

  const int n0 = nb + (w << 5) + lr;
#pragma unroll
  for (int kk = 0; kk < 128; kk += 32) {
    const int d0 = kk + (grp << 3);
    short8 Bh[2];
#pragma unroll
    for (int t = 0; t < 2; ++t) {
      const int n = n0 + (t << 4);
      const float* src = x + bbase + (size_t)d0 * NN + n;
      float f[8];
#pragma unroll
      for (int i = 0; i < 8; ++i) f[i] = src[(size_t)i * NN];
      u16 h[8];
#pragma unroll
      for (int i = 0; i < 8; ++i) h[i] = bf16rne(f[i]);
      Bh[t] = (short8){(short)h[0], (short)h[1], (short)h[2], (short)h[3],
                       (short)h[4], (short)h[5], (short)h[6], (short)h[7]};
    }
#pragma unroll
    for (int mt = 0; mt < 8; ++mt) {
      const int mrow = (mt << 4) + lr;
      const short8 Ah = *(const short8*)(at + (mrow << 7) + ((kk + (grp << 3)) ^ swz));
#pragma unroll
      for (int t = 0; t < 2; ++t)
        acc[mt][t] = __builtin_amdgcn_mfma_f32_16x16x32_bf16(Ah, Bh[t], acc[mt][t], 0, 0, 0);
    }
  }

  // epilogue: ADJACENT load-x / store-out per element (the 1x-WRITE pattern)
  const float gm = gamma[0];
#pragma unroll
  for (int mt = 0; mt < 8; ++mt)
#pragma unroll
    for (int t = 0; t < 2; ++t)
#pragma unroll
      for (int r = 0; r < 4; ++r) {
        const int c = (mt << 4) + (grp << 2) + r;
        const int n = n0 + (t << 4);
        const size_t off = bbase + (size_t)c * NN + n;
        out[off] = x[off] + gm * acc[mt][t][r];
      }
}

extern "C" void kernel_launch(void* const* d_in, const int* in_sizes, int n_in,
                              void* d_out, int out_size, void* d_ws, size_t ws_size,
                              hipStream_t stream) {
  (void)in_sizes; (void)n_in; (void)out_size; (void)ws_size;
  const float* x     = (const float*)d_in[0];
  const float* gamma = (const float*)d_in[1];
  float* out  = (float*)d_out;
  u16*   attn = (u16*)d_ws;          // 2*128*128 bf16 = 64 KiB
  float* part = out;                  // reuse d_out as partial-Gram scratch (33.5 MB)

  gram_k<<<dim3(2 * G1_PARTS), dim3(256), 0, stream>>>(x, part);
  soft_k<<<dim3(2 * 128),      dim3(128), 0, stream>>>(part, attn);
  pv_k  <<<dim3(2 * N3_PER_B), dim3(256), 0, stream>>>(x, attn, gamma, out);
}